// Round 14
// baseline (272.868 us; speedup 1.0000x reference)
//
#include <hip/hip_runtime.h>
#include <hip/hip_bf16.h>
#include <math.h>

#define Bc  4
#define HWc 2048
#define Cc  768
#define Hc  8
#define HDc 96

typedef short bf16x8 __attribute__((ext_vector_type(8)));
typedef float f32x4  __attribute__((ext_vector_type(4)));

static __device__ __forceinline__ unsigned short f2bf(float x) {
    __hip_bfloat16 h = __float2bfloat16(x);
    return *reinterpret_cast<unsigned short*>(&h);
}

#define GLOBAL_AS(p) ((const __attribute__((address_space(1))) void*)(p))
#define LDS_AS(p)    ((__attribute__((address_space(3))) void*)(p))

// ---------------------------------------------------------------------------
// Kernel 0: fused fp32 -> bf16 cast of x, Wqkv, Wproj (one launch)
// ---------------------------------------------------------------------------
__global__ __launch_bounds__(256) void cast_all(
    const float* __restrict__ x, const float* __restrict__ Wq,
    const float* __restrict__ Wp, unsigned short* __restrict__ xb,
    unsigned short* __restrict__ Wqb, unsigned short* __restrict__ Wpb,
    int nx4, int nwq4, int nwp4)
{
    int i = blockIdx.x * 256 + threadIdx.x;
    const float* src; unsigned short* dst; int j = i;
    if (i < nx4) { src = x; dst = xb; }
    else if ((j = i - nx4) < nwq4) { src = Wq; dst = Wqb; }
    else if ((j = i - nx4 - nwq4) < nwp4) { src = Wp; dst = Wpb; }
    else return;
    float4 v = ((const float4*)src)[j];
    ushort4 p;
    p.x = f2bf(v.x); p.y = f2bf(v.y); p.z = f2bf(v.z); p.w = f2bf(v.w);
    ((ushort4*)dst)[j] = p;
}

// ---------------------------------------------------------------------------
// Kernel 1: qkv GEMM — r20 champion VERBATIM (BK=64 two fixed half-panels,
// 2-barrier issue->drain-immediately, XCD-chunked 1D grid, Tt aliasing the
// staging panels, LDS 32KB, no launch-bounds cap). Codegen envelope frozen.
// ---------------------------------------------------------------------------
__global__ __launch_bounds__(256) void qkv_mfma_T(
    const unsigned short* __restrict__ Wb, const unsigned short* __restrict__ xb,
    const float* __restrict__ cs, const float* __restrict__ sn,
    unsigned short* __restrict__ qo, unsigned short* __restrict__ ko,
    unsigned short* __restrict__ vt)
{
    __shared__ unsigned short smem[16384];   // 32 KB: [Al0|Al1|Bl0|Bl1]
    unsigned short* const Alp[2] = { smem,        smem + 4096 };
    unsigned short* const Blp[2] = { smem + 8192, smem + 12288 };
    unsigned short (*Tt)[132] = (unsigned short (*)[132])smem;  // epilogue-only alias

    const int tid  = threadIdx.x;
    const int lane = tid & 63;
    const int w    = tid >> 6;
    const int c    = lane & 15, qd = lane >> 4;
    const int wm   = w & 1, wn = w >> 1;

    // XCD-chunked decode: 1152 blocks = 8 xcd x 8 token-tiles x 18 feat-tiles
    const int bid = blockIdx.x;
    const int xcd = bid & 7;
    const int jj  = bid >> 3;                 // 0..143
    const int xt  = (xcd << 3) + (jj & 7);    // token tile 0..63
    const int yt  = jj >> 3;                  // feature tile 0..17
    const int m0  = yt << 7;                  // feature base (0..2303)
    const int n0  = xt << 7;                  // token base

    const int srow = (w << 5) + (lane >> 2);
    const int sseg = (lane & 3) << 3;
    const unsigned short* Ag = Wb + (size_t)(m0 + srow) * Cc + sseg;
    const unsigned short* Bg = xb + (size_t)(n0 + srow) * Cc + sseg;
    const int wofs = (w << 5) * 32;     // wave staging offset inside a panel

    f32x4 acc[4][4];
    #pragma unroll
    for (int i = 0; i < 4; i++)
        #pragma unroll
        for (int j = 0; j < 4; j++) acc[i][j] = (f32x4)0.f;

    for (int k0 = 0; k0 < Cc; k0 += 64) {
        __syncthreads();
        #pragma unroll
        for (int hh = 0; hh < 2; hh++) {
            const int kk = k0 + (hh << 5);
            __builtin_amdgcn_global_load_lds(GLOBAL_AS(Ag + kk),           LDS_AS(Alp[hh] + wofs),       16, 0, 0);
            __builtin_amdgcn_global_load_lds(GLOBAL_AS(Ag + 16 * Cc + kk), LDS_AS(Alp[hh] + wofs + 512), 16, 0, 0);
            __builtin_amdgcn_global_load_lds(GLOBAL_AS(Bg + kk),           LDS_AS(Blp[hh] + wofs),       16, 0, 0);
            __builtin_amdgcn_global_load_lds(GLOBAL_AS(Bg + 16 * Cc + kk), LDS_AS(Blp[hh] + wofs + 512), 16, 0, 0);
        }
        __syncthreads();   // implicit vmcnt(0) drain (proven pattern)

        #pragma unroll
        for (int hh = 0; hh < 2; hh++) {
            bf16x8 af[4], bfr[4];
            #pragma unroll
            for (int mt = 0; mt < 4; mt++)
                af[mt] = *(const bf16x8*)&Alp[hh][((wm << 6) + mt * 16 + c) * 32 + qd * 8];
            #pragma unroll
            for (int nt = 0; nt < 4; nt++)
                bfr[nt] = *(const bf16x8*)&Blp[hh][((wn << 6) + nt * 16 + c) * 32 + qd * 8];
            __builtin_amdgcn_s_setprio(1);
            #pragma unroll
            for (int mt = 0; mt < 4; mt++)
                #pragma unroll
                for (int nt = 0; nt < 4; nt++)
                    acc[mt][nt] = __builtin_amdgcn_mfma_f32_16x16x32_bf16(
                        af[mt], bfr[nt], acc[mt][nt], 0, 0, 0);
            __builtin_amdgcn_s_setprio(0);
        }
    }

    const int which = m0 / Cc;
    const int m0l = m0 - which * Cc;
    const float qs = 0.10206207261596577f;

    if (which == 2) {
        #pragma unroll
        for (int mt = 0; mt < 4; mt++) {
            const int c0 = m0l + (wm << 6) + mt * 16 + (qd << 2);
            const int h = c0 / HDc, d = c0 % HDc;
            #pragma unroll
            for (int nt = 0; nt < 4; nt++) {
                const int t = n0 + (wn << 6) + nt * 16 + c;
                const int b = t >> 11, tt = t & (HWc - 1);
                const size_t base = ((size_t)((b * Hc + h) * HDc + d)) * HWc + tt;
                #pragma unroll
                for (int r = 0; r < 4; r++)
                    vt[base + (size_t)r * HWc] = f2bf(acc[mt][nt][r]);
            }
        }
    } else {
        unsigned short* dst = which ? ko : qo;
        const float sc = which ? 1.0f : qs;
        for (int tk = 0; tk < 2; tk++) {
            __syncthreads();   // all K-loop LDS reads done; Tt alias now safe
            if (wn == tk) {
                #pragma unroll
                for (int mt = 0; mt < 4; mt++) {
                    const int c0 = m0l + (wm << 6) + mt * 16 + (qd << 2);
                    const int d = c0 % HDc;
                    #pragma unroll
                    for (int nt = 0; nt < 4; nt++) {
                        const int t = n0 + (wn << 6) + nt * 16 + c;
                        const int tt = t & (HWc - 1);
                        const float4 c4 = *(const float4*)&cs[tt * HDc + d];
                        const float4 s4 = *(const float4*)&sn[tt * HDc + d];
                        float o0 = (acc[mt][nt][0] * c4.x - acc[mt][nt][1] * s4.x) * sc;
                        float o1 = (acc[mt][nt][1] * c4.y + acc[mt][nt][0] * s4.y) * sc;
                        float o2 = (acc[mt][nt][2] * c4.z - acc[mt][nt][3] * s4.z) * sc;
                        float o3 = (acc[mt][nt][3] * c4.w + acc[mt][nt][2] * s4.w) * sc;
                        ushort4 pk;
                        pk.x = f2bf(o0); pk.y = f2bf(o1);
                        pk.z = f2bf(o2); pk.w = f2bf(o3);
                        *(ushort4*)&Tt[nt * 16 + c][(wm << 6) + mt * 16 + (qd << 2)] = pk;
                    }
                }
            }
            __syncthreads();
            #pragma unroll
            for (int it = 0; it < 8; it++) {
                int s = tid + (it << 8);
                int row = s >> 5, fseg = (s & 31) << 2;
                int fg = m0l + fseg;
                int h = fg / HDc, d = fg % HDc;
                int token = n0 + tk * 64 + row;
                int b = token >> 11, tt = token & (HWc - 1);
                *(ushort4*)&dst[((size_t)(b * Hc + h) * HWc + tt) * HDc + d] =
                    *(ushort4*)&Tt[row][fseg];
            }
        }
    }
}

// ---------------------------------------------------------------------------
// Kernel 2: MFMA flash attention. r23 change: softmax (exp + reduce + P-pack,
// ~350 cy of pure VALU/per-wave-LDS with NO barrier dependence) moved from
// after B2 to BEFORE B2, so it fills V(ck)'s issue->drain window (previously
// only QK^T's ~150 cy sat there; V's drain latency was naked at B2).
// Fixed-destination DMA schedule otherwise identical to the proven r13 form:
// V issued post-B1/drained at B2, K(ck+1) issued post-B2/drained at next B1.
// ---------------------------------------------------------------------------
__global__ __launch_bounds__(256, 4) void attn_flash(
    const unsigned short* __restrict__ qg, const unsigned short* __restrict__ kg,
    const unsigned short* __restrict__ vtg, unsigned short* __restrict__ ob)
{
    __shared__ unsigned short Ks[64][96];     // 12,288 B (linear, DMA-staged)
    __shared__ unsigned short Vt[96][64];     // 12,288 B (XOR-swizzled slots)
    __shared__ unsigned short Pt[4][16][72];  //  9,216 B

    const int tid  = threadIdx.x;
    const int lane = tid & 63;
    const int w    = tid >> 6;
    const int c    = lane & 15;
    const int qd   = lane >> 4;
    const int bh   = blockIdx.x;          // XCD affinity: bh mod 8 = XCD
    const int b    = bh >> 3, h = bh & 7;
    const int q0   = blockIdx.y << 6;     // 64 q per block

    const unsigned short* kb  = kg  + (size_t)bh * HWc * HDc;
    const unsigned short* vtb = vtg + (size_t)bh * HDc * HWc;

    bf16x8 qt[3];
    {
        const unsigned short* qr = qg + ((size_t)bh * HWc + q0 + w * 16 + c) * HDc + qd * 8;
        #pragma unroll
        for (int ks = 0; ks < 3; ks++)
            qt[ks] = *(const bf16x8*)(qr + ks * 32);
    }

    unsigned short* Kbase = &Ks[0][0];
    unsigned short* Vbase = &Vt[0][0];
    const int vrow_l = lane >> 3;                         // 0..7 within chunk
    const int vseg_l = ((lane & 7) ^ vrow_l) << 3;        // swizzled col (shorts)

    f32x4 oacc[6];
    #pragma unroll
    for (int mt = 0; mt < 6; mt++) oacc[mt] = (f32x4)0.f;
    float lsum = 0.f;

    // Prologue: DMA K tile 0 (drained by first in-loop barrier)
    {
        const unsigned short* kc = kb;  // ck = 0
        #pragma unroll
        for (int it = 0; it < 3; it++) {
            const int chunk = w * 3 + it;
            __builtin_amdgcn_global_load_lds(
                GLOBAL_AS(kc + chunk * 512 + lane * 8),
                LDS_AS(Kbase + chunk * 512), 16, 0, 0);
        }
    }

    for (int ck = 0; ck < 32; ck++) {
        __syncthreads();   // B1: drains K(ck); Vt(ck-1)/Pt fully consumed
        // Issue V(ck): fixed dest; drained at B2 (window = QK^T + softmax)
        {
            const unsigned short* vc = vtb + (ck << 6);
            #pragma unroll
            for (int it = 0; it < 3; it++) {
                const int chunk = w * 3 + it;
                __builtin_amdgcn_global_load_lds(
                    GLOBAL_AS(vc + (size_t)(chunk * 8 + vrow_l) * HWc + vseg_l),
                    LDS_AS(Vbase + chunk * 512), 16, 0, 0);
            }
        }

        // S^T = K . Q^T : [64 seq x 16 q], C-layout col=q(c), row=seq
        f32x4 sacc[4];
        #pragma unroll
        for (int mt = 0; mt < 4; mt++) sacc[mt] = (f32x4)0.f;
        __builtin_amdgcn_s_setprio(1);
        #pragma unroll
        for (int mt = 0; mt < 4; mt++)
            #pragma unroll
            for (int ks = 0; ks < 3; ks++) {
                bf16x8 af = *(const bf16x8*)&Ks[mt * 16 + c][ks * 32 + qd * 8];
                sacc[mt] = __builtin_amdgcn_mfma_f32_16x16x32_bf16(
                    af, qt[ks], sacc[mt], 0, 0, 0);
            }
        __builtin_amdgcn_s_setprio(0);

        // Softmax moved BEFORE B2: plain exp + column sum (registers only)
        float rs = 0.f;
        #pragma unroll
        for (int mt = 0; mt < 4; mt++)
            #pragma unroll
            for (int r = 0; r < 4; r++) {
                float p = __expf(sacc[mt][r]);
                sacc[mt][r] = p;
                rs += p;
            }
        rs += __shfl_xor(rs, 16);
        rs += __shfl_xor(rs, 32);
        lsum += rs;

        // P^T pack to LDS (per-wave region, same-wave read-back — no barrier)
        #pragma unroll
        for (int mt = 0; mt < 4; mt++) {
            __hip_bfloat162 p01 = __float22bfloat162_rn(float2{sacc[mt][0], sacc[mt][1]});
            __hip_bfloat162 p23 = __float22bfloat162_rn(float2{sacc[mt][2], sacc[mt][3]});
            uint2 pk;
            pk.x = *reinterpret_cast<unsigned int*>(&p01);
            pk.y = *reinterpret_cast<unsigned int*>(&p23);
            *(uint2*)&Pt[w][c][mt * 16 + qd * 4] = pk;
        }
        bf16x8 pf[2];
        #pragma unroll
        for (int ks = 0; ks < 2; ks++)
            pf[ks] = *(const bf16x8*)&Pt[w][c][ks * 32 + qd * 8];

        __syncthreads();   // B2: drains V(ck); all waves done reading Ks(ck)
        // Issue K(ck+1): fixed dest; drained at next B1 (window = PV)
        if (ck < 31) {
            const unsigned short* kc = kb + (size_t)((ck + 1) << 6) * HDc;
            #pragma unroll
            for (int it = 0; it < 3; it++) {
                const int chunk = w * 3 + it;
                __builtin_amdgcn_global_load_lds(
                    GLOBAL_AS(kc + chunk * 512 + lane * 8),
                    LDS_AS(Kbase + chunk * 512), 16, 0, 0);
            }
        }

        // O^T += V^T . P^T (V read through the slot XOR swizzle)
        __builtin_amdgcn_s_setprio(1);
        #pragma unroll
        for (int mt = 0; mt < 6; mt++)
            #pragma unroll
            for (int ks = 0; ks < 2; ks++) {
                const int row = mt * 16 + c;
                bf16x8 vf = *(const bf16x8*)&Vt[row][(((ks << 2) + qd) ^ (c & 7)) << 3];
                oacc[mt] = __builtin_amdgcn_mfma_f32_16x16x32_bf16(
                    vf, pf[ks], oacc[mt], 0, 0, 0);
            }
        __builtin_amdgcn_s_setprio(0);
    }

    const float linv = 1.0f / lsum;
    unsigned short* orow = ob + ((size_t)(b * HWc + q0 + w * 16 + c)) * Cc + h * HDc;
    #pragma unroll
    for (int mt = 0; mt < 6; mt++) {
        f32x4 val = oacc[mt] * linv;
        ushort4 pk;
        pk.x = f2bf(val[0]); pk.y = f2bf(val[1]);
        pk.z = f2bf(val[2]); pk.w = f2bf(val[3]);
        *(ushort4*)&orow[mt * 16 + qd * 4] = pk;
    }
}

// ---------------------------------------------------------------------------
// Kernel 3: out = o @ Wproj^T + bias — r19/r20-champion version verbatim
// (2-barrier, single buffer, BK=32, XCD-chunked 1D grid). r22's BK=64 was
// neutral-to-worse; reverted.
// ---------------------------------------------------------------------------
__global__ __launch_bounds__(256) void proj_mfma_T64(
    const unsigned short* __restrict__ Wb, const unsigned short* __restrict__ Ab,
    const float* __restrict__ bias, float* __restrict__ out)
{
    __shared__ unsigned short Al[128 * 32];
    __shared__ unsigned short Bl[64 * 32];
    const int tid  = threadIdx.x;
    const int lane = tid & 63;
    const int w    = tid >> 6;
    const int c    = lane & 15, qd = lane >> 4;
    const int wm   = w & 1, wn = w >> 1;

    const int bid = blockIdx.x;
    const int xcd = bid & 7;
    const int jj  = bid >> 3;                  // 0..95
    const int xt  = (xcd << 4) + (jj & 15);    // token tile 0..127
    const int yt  = jj >> 4;                   // feature tile 0..5
    const int m0  = yt << 7;                   // out-feature base (0..640)
    const int n0  = xt << 6;                   // token base (64-tile)

    const int srow = (w << 5) + (lane >> 2);
    const int sseg = (lane & 3) << 3;
    const unsigned short* Ag = Wb + (size_t)(m0 + srow) * Cc + sseg;
    unsigned short* Adst = &Al[(w << 5) * 32];
    const int brow = (w << 4) + (lane >> 2);
    const unsigned short* Bg = Ab + (size_t)(n0 + brow) * Cc + sseg;
    unsigned short* Bdst = &Bl[(w << 4) * 32];

    f32x4 acc[4][2];
    #pragma unroll
    for (int i = 0; i < 4; i++)
        #pragma unroll
        for (int j = 0; j < 2; j++) acc[i][j] = (f32x4)0.f;

    for (int k0 = 0; k0 < Cc; k0 += 32) {
        __syncthreads();
        __builtin_amdgcn_global_load_lds(GLOBAL_AS(Ag + k0),           LDS_AS(Adst),           16, 0, 0);
        __builtin_amdgcn_global_load_lds(GLOBAL_AS(Ag + 16 * Cc + k0), LDS_AS(Adst + 16 * 32), 16, 0, 0);
        __builtin_amdgcn_global_load_lds(GLOBAL_AS(Bg + k0),           LDS_AS(Bdst),           16, 0, 0);
        __syncthreads();

        bf16x8 af[4], bfr[2];
        #pragma unroll
        for (int mt = 0; mt < 4; mt++)
            af[mt] = *(const bf16x8*)&Al[((wm << 6) + mt * 16 + c) * 32 + qd * 8];
        #pragma unroll
        for (int nt = 0; nt < 2; nt++)
            bfr[nt] = *(const bf16x8*)&Bl[((wn << 5) + nt * 16 + c) * 32 + qd * 8];
        #pragma unroll
        for (int mt = 0; mt < 4; mt++)
            #pragma unroll
            for (int nt = 0; nt < 2; nt++)
                acc[mt][nt] = __builtin_amdgcn_mfma_f32_16x16x32_bf16(
                    af[mt], bfr[nt], acc[mt][nt], 0, 0, 0);
    }

    #pragma unroll
    for (int mt = 0; mt < 4; mt++) {
        const int f = m0 + (wm << 6) + mt * 16 + (qd << 2);
        const float4 b4 = *(const float4*)&bias[f];
        #pragma unroll
        for (int nt = 0; nt < 2; nt++) {
            const int t = n0 + (wn << 5) + nt * 16 + c;
            float4 val;
            val.x = acc[mt][nt][0] + b4.x;
            val.y = acc[mt][nt][1] + b4.y;
            val.z = acc[mt][nt][2] + b4.z;
            val.w = acc[mt][nt][3] + b4.w;
            *(float4*)&out[(size_t)t * Cc + f] = val;
        }
    }
}

// ---------------------------------------------------------------------------
extern "C" void kernel_launch(void* const* d_in, const int* in_sizes, int n_in,
                              void* d_out, int out_size, void* d_ws, size_t ws_size,
                              hipStream_t stream) {
    const float* x     = (const float*)d_in[0];
    const float* cs    = (const float*)d_in[1];
    const float* sn    = (const float*)d_in[2];
    const float* Wqkv  = (const float*)d_in[3];
    const float* Wproj = (const float*)d_in[4];
    const float* bproj = (const float*)d_in[5];
    float* out = (float*)d_out;

    const size_t per = (size_t)Bc * Hc * HWc * HDc;  // 6291456
    const size_t nx  = per;
    const size_t nwq = (size_t)3 * Cc * Cc;
    const size_t nwp = (size_t)Cc * Cc;

    unsigned short* xb  = (unsigned short*)d_ws;
    unsigned short* Wqb = xb + nx;
    unsigned short* Wpb = Wqb + nwq;
    unsigned short* q   = Wpb + nwp;
    unsigned short* k   = q + per;
    unsigned short* vt  = k + per;
    unsigned short* ob  = vt + per;

    const int nx4 = (int)(nx / 4), nwq4 = (int)(nwq / 4), nwp4 = (int)(nwp / 4);
    const int ntot = nx4 + nwq4 + nwp4;
    cast_all<<<dim3((ntot + 255) / 256), 256, 0, stream>>>(
        x, Wqkv, Wproj, xb, Wqb, Wpb, nx4, nwq4, nwp4);

    // qkv: 1D grid, XCD-chunked decode (8 xcd x 8 token-tiles x 18 feat-tiles)
    qkv_mfma_T<<<dim3(1152), 256, 0, stream>>>(Wqb, xb, cs, sn, q, k, vt);
    // attention: x = bh (XCD affinity), y = 32 q-tiles of 64 -> 1024 blocks
    attn_flash<<<dim3(32, 32), 256, 0, stream>>>(q, k, vt, ob);
    // proj: 1D grid, XCD-chunked decode (8 xcd x 16 token-tiles x 6 feat-tiles)
    proj_mfma_T64<<<dim3(768), 256, 0, stream>>>(Wpb, ob, bproj, out);
}

// Round 15
// 265.575 us; speedup vs baseline: 1.0275x; 1.0275x over previous
//
#include <hip/hip_runtime.h>
#include <hip/hip_bf16.h>
#include <math.h>

#define Bc  4
#define HWc 2048
#define Cc  768
#define Hc  8
#define HDc 96

typedef short bf16x8 __attribute__((ext_vector_type(8)));
typedef float f32x4  __attribute__((ext_vector_type(4)));

static __device__ __forceinline__ unsigned short f2bf(float x) {
    __hip_bfloat16 h = __float2bfloat16(x);
    return *reinterpret_cast<unsigned short*>(&h);
}

#define GLOBAL_AS(p) ((const __attribute__((address_space(1))) void*)(p))
#define LDS_AS(p)    ((__attribute__((address_space(3))) void*)(p))

// ---------------------------------------------------------------------------
// Kernel 0: fused fp32 -> bf16 cast of x, Wqkv, Wproj (one launch)
// ---------------------------------------------------------------------------
__global__ __launch_bounds__(256) void cast_all(
    const float* __restrict__ x, const float* __restrict__ Wq,
    const float* __restrict__ Wp, unsigned short* __restrict__ xb,
    unsigned short* __restrict__ Wqb, unsigned short* __restrict__ Wpb,
    int nx4, int nwq4, int nwp4)
{
    int i = blockIdx.x * 256 + threadIdx.x;
    const float* src; unsigned short* dst; int j = i;
    if (i < nx4) { src = x; dst = xb; }
    else if ((j = i - nx4) < nwq4) { src = Wq; dst = Wqb; }
    else if ((j = i - nx4 - nwq4) < nwp4) { src = Wp; dst = Wpb; }
    else return;
    float4 v = ((const float4*)src)[j];
    ushort4 p;
    p.x = f2bf(v.x); p.y = f2bf(v.y); p.z = f2bf(v.z); p.w = f2bf(v.w);
    ((ushort4*)dst)[j] = p;
}

// ---------------------------------------------------------------------------
// Kernel 1: qkv GEMM — r20 champion VERBATIM (BK=64 two fixed half-panels,
// 2-barrier issue->drain-immediately, XCD-chunked 1D grid, Tt aliasing the
// staging panels, LDS 32KB, no launch-bounds cap). Codegen envelope frozen:
// cross-barrier DMA pipelining (r14/r15/r18) and the (256,4) VGPR cap (r21)
// both corrupt this kernel on this toolchain.
// ---------------------------------------------------------------------------
__global__ __launch_bounds__(256) void qkv_mfma_T(
    const unsigned short* __restrict__ Wb, const unsigned short* __restrict__ xb,
    const float* __restrict__ cs, const float* __restrict__ sn,
    unsigned short* __restrict__ qo, unsigned short* __restrict__ ko,
    unsigned short* __restrict__ vt)
{
    __shared__ unsigned short smem[16384];   // 32 KB: [Al0|Al1|Bl0|Bl1]
    unsigned short* const Alp[2] = { smem,        smem + 4096 };
    unsigned short* const Blp[2] = { smem + 8192, smem + 12288 };
    unsigned short (*Tt)[132] = (unsigned short (*)[132])smem;  // epilogue-only alias

    const int tid  = threadIdx.x;
    const int lane = tid & 63;
    const int w    = tid >> 6;
    const int c    = lane & 15, qd = lane >> 4;
    const int wm   = w & 1, wn = w >> 1;

    // XCD-chunked decode: 1152 blocks = 8 xcd x 8 token-tiles x 18 feat-tiles
    const int bid = blockIdx.x;
    const int xcd = bid & 7;
    const int jj  = bid >> 3;                 // 0..143
    const int xt  = (xcd << 3) + (jj & 7);    // token tile 0..63
    const int yt  = jj >> 3;                  // feature tile 0..17
    const int m0  = yt << 7;                  // feature base (0..2303)
    const int n0  = xt << 7;                  // token base

    const int srow = (w << 5) + (lane >> 2);
    const int sseg = (lane & 3) << 3;
    const unsigned short* Ag = Wb + (size_t)(m0 + srow) * Cc + sseg;
    const unsigned short* Bg = xb + (size_t)(n0 + srow) * Cc + sseg;
    const int wofs = (w << 5) * 32;     // wave staging offset inside a panel

    f32x4 acc[4][4];
    #pragma unroll
    for (int i = 0; i < 4; i++)
        #pragma unroll
        for (int j = 0; j < 4; j++) acc[i][j] = (f32x4)0.f;

    for (int k0 = 0; k0 < Cc; k0 += 64) {
        __syncthreads();
        #pragma unroll
        for (int hh = 0; hh < 2; hh++) {
            const int kk = k0 + (hh << 5);
            __builtin_amdgcn_global_load_lds(GLOBAL_AS(Ag + kk),           LDS_AS(Alp[hh] + wofs),       16, 0, 0);
            __builtin_amdgcn_global_load_lds(GLOBAL_AS(Ag + 16 * Cc + kk), LDS_AS(Alp[hh] + wofs + 512), 16, 0, 0);
            __builtin_amdgcn_global_load_lds(GLOBAL_AS(Bg + kk),           LDS_AS(Blp[hh] + wofs),       16, 0, 0);
            __builtin_amdgcn_global_load_lds(GLOBAL_AS(Bg + 16 * Cc + kk), LDS_AS(Blp[hh] + wofs + 512), 16, 0, 0);
        }
        __syncthreads();   // implicit vmcnt(0) drain (proven pattern)

        #pragma unroll
        for (int hh = 0; hh < 2; hh++) {
            bf16x8 af[4], bfr[4];
            #pragma unroll
            for (int mt = 0; mt < 4; mt++)
                af[mt] = *(const bf16x8*)&Alp[hh][((wm << 6) + mt * 16 + c) * 32 + qd * 8];
            #pragma unroll
            for (int nt = 0; nt < 4; nt++)
                bfr[nt] = *(const bf16x8*)&Blp[hh][((wn << 6) + nt * 16 + c) * 32 + qd * 8];
            __builtin_amdgcn_s_setprio(1);
            #pragma unroll
            for (int mt = 0; mt < 4; mt++)
                #pragma unroll
                for (int nt = 0; nt < 4; nt++)
                    acc[mt][nt] = __builtin_amdgcn_mfma_f32_16x16x32_bf16(
                        af[mt], bfr[nt], acc[mt][nt], 0, 0, 0);
            __builtin_amdgcn_s_setprio(0);
        }
    }

    const int which = m0 / Cc;
    const int m0l = m0 - which * Cc;
    const float qs = 0.10206207261596577f;

    if (which == 2) {
        #pragma unroll
        for (int mt = 0; mt < 4; mt++) {
            const int c0 = m0l + (wm << 6) + mt * 16 + (qd << 2);
            const int h = c0 / HDc, d = c0 % HDc;
            #pragma unroll
            for (int nt = 0; nt < 4; nt++) {
                const int t = n0 + (wn << 6) + nt * 16 + c;
                const int b = t >> 11, tt = t & (HWc - 1);
                const size_t base = ((size_t)((b * Hc + h) * HDc + d)) * HWc + tt;
                #pragma unroll
                for (int r = 0; r < 4; r++)
                    vt[base + (size_t)r * HWc] = f2bf(acc[mt][nt][r]);
            }
        }
    } else {
        unsigned short* dst = which ? ko : qo;
        const float sc = which ? 1.0f : qs;
        for (int tk = 0; tk < 2; tk++) {
            __syncthreads();   // all K-loop LDS reads done; Tt alias now safe
            if (wn == tk) {
                #pragma unroll
                for (int mt = 0; mt < 4; mt++) {
                    const int c0 = m0l + (wm << 6) + mt * 16 + (qd << 2);
                    const int d = c0 % HDc;
                    #pragma unroll
                    for (int nt = 0; nt < 4; nt++) {
                        const int t = n0 + (wn << 6) + nt * 16 + c;
                        const int tt = t & (HWc - 1);
                        const float4 c4 = *(const float4*)&cs[tt * HDc + d];
                        const float4 s4 = *(const float4*)&sn[tt * HDc + d];
                        float o0 = (acc[mt][nt][0] * c4.x - acc[mt][nt][1] * s4.x) * sc;
                        float o1 = (acc[mt][nt][1] * c4.y + acc[mt][nt][0] * s4.y) * sc;
                        float o2 = (acc[mt][nt][2] * c4.z - acc[mt][nt][3] * s4.z) * sc;
                        float o3 = (acc[mt][nt][3] * c4.w + acc[mt][nt][2] * s4.w) * sc;
                        ushort4 pk;
                        pk.x = f2bf(o0); pk.y = f2bf(o1);
                        pk.z = f2bf(o2); pk.w = f2bf(o3);
                        *(ushort4*)&Tt[nt * 16 + c][(wm << 6) + mt * 16 + (qd << 2)] = pk;
                    }
                }
            }
            __syncthreads();
            #pragma unroll
            for (int it = 0; it < 8; it++) {
                int s = tid + (it << 8);
                int row = s >> 5, fseg = (s & 31) << 2;
                int fg = m0l + fseg;
                int h = fg / HDc, d = fg % HDc;
                int token = n0 + tk * 64 + row;
                int b = token >> 11, tt = token & (HWc - 1);
                *(ushort4*)&dst[((size_t)(b * Hc + h) * HWc + tt) * HDc + d] =
                    *(ushort4*)&Tt[row][fseg];
            }
        }
    }
}

// ---------------------------------------------------------------------------
// Kernel 2: MFMA flash attention — r13 schedule restored (softmax AFTER B2;
// r23's reorder was -4us). r24 micro-opt: lsum's cross-lane reduction
// (2x __shfl_xor per KV-tile) hoisted out of the loop — lsum accumulates
// per-lane partials for 32 iterations, one qd-group reduce at the end.
// Pure register arithmetic reordering, zero sync risk.
// ---------------------------------------------------------------------------
__global__ __launch_bounds__(256, 4) void attn_flash(
    const unsigned short* __restrict__ qg, const unsigned short* __restrict__ kg,
    const unsigned short* __restrict__ vtg, unsigned short* __restrict__ ob)
{
    __shared__ unsigned short Ks[64][96];     // 12,288 B (linear, DMA-staged)
    __shared__ unsigned short Vt[96][64];     // 12,288 B (XOR-swizzled slots)
    __shared__ unsigned short Pt[4][16][72];  //  9,216 B

    const int tid  = threadIdx.x;
    const int lane = tid & 63;
    const int w    = tid >> 6;
    const int c    = lane & 15;
    const int qd   = lane >> 4;
    const int bh   = blockIdx.x;          // XCD affinity: bh mod 8 = XCD
    const int b    = bh >> 3, h = bh & 7;
    const int q0   = blockIdx.y << 6;     // 64 q per block

    const unsigned short* kb  = kg  + (size_t)bh * HWc * HDc;
    const unsigned short* vtb = vtg + (size_t)bh * HDc * HWc;

    bf16x8 qt[3];
    {
        const unsigned short* qr = qg + ((size_t)bh * HWc + q0 + w * 16 + c) * HDc + qd * 8;
        #pragma unroll
        for (int ks = 0; ks < 3; ks++)
            qt[ks] = *(const bf16x8*)(qr + ks * 32);
    }

    unsigned short* Kbase = &Ks[0][0];
    unsigned short* Vbase = &Vt[0][0];
    const int vrow_l = lane >> 3;                         // 0..7 within chunk
    const int vseg_l = ((lane & 7) ^ vrow_l) << 3;        // swizzled col (shorts)

    f32x4 oacc[6];
    #pragma unroll
    for (int mt = 0; mt < 6; mt++) oacc[mt] = (f32x4)0.f;
    float lsum = 0.f;   // per-lane partial; qd-group reduce hoisted to end

    // Prologue: DMA K tile 0 (drained by first in-loop barrier)
    {
        const unsigned short* kc = kb;  // ck = 0
        #pragma unroll
        for (int it = 0; it < 3; it++) {
            const int chunk = w * 3 + it;
            __builtin_amdgcn_global_load_lds(
                GLOBAL_AS(kc + chunk * 512 + lane * 8),
                LDS_AS(Kbase + chunk * 512), 16, 0, 0);
        }
    }

    for (int ck = 0; ck < 32; ck++) {
        __syncthreads();   // B1: drains K(ck); Vt(ck-1) fully consumed by all
        // Issue V(ck): hidden under QK^T, drained at B2
        {
            const unsigned short* vc = vtb + (ck << 6);
            #pragma unroll
            for (int it = 0; it < 3; it++) {
                const int chunk = w * 3 + it;
                __builtin_amdgcn_global_load_lds(
                    GLOBAL_AS(vc + (size_t)(chunk * 8 + vrow_l) * HWc + vseg_l),
                    LDS_AS(Vbase + chunk * 512), 16, 0, 0);
            }
        }

        // S^T = K . Q^T : [64 seq x 16 q], C-layout col=q(c), row=seq
        f32x4 sacc[4];
        #pragma unroll
        for (int mt = 0; mt < 4; mt++) sacc[mt] = (f32x4)0.f;
        __builtin_amdgcn_s_setprio(1);
        #pragma unroll
        for (int mt = 0; mt < 4; mt++)
            #pragma unroll
            for (int ks = 0; ks < 3; ks++) {
                bf16x8 af = *(const bf16x8*)&Ks[mt * 16 + c][ks * 32 + qd * 8];
                sacc[mt] = __builtin_amdgcn_mfma_f32_16x16x32_bf16(
                    af, qt[ks], sacc[mt], 0, 0, 0);
            }
        __builtin_amdgcn_s_setprio(0);

        __syncthreads();   // B2: drains V(ck); all waves done reading Ks(ck)
        // Issue K(ck+1): hidden under softmax+P+PV, drained at next B1
        if (ck < 31) {
            const unsigned short* kc = kb + (size_t)((ck + 1) << 6) * HDc;
            #pragma unroll
            for (int it = 0; it < 3; it++) {
                const int chunk = w * 3 + it;
                __builtin_amdgcn_global_load_lds(
                    GLOBAL_AS(kc + chunk * 512 + lane * 8),
                    LDS_AS(Kbase + chunk * 512), 16, 0, 0);
            }
        }

        // plain exp (no max subtraction) + per-lane partial column sum
        float rs = 0.f;
        #pragma unroll
        for (int mt = 0; mt < 4; mt++)
            #pragma unroll
            for (int r = 0; r < 4; r++) {
                float p = __expf(sacc[mt][r]);
                sacc[mt][r] = p;
                rs += p;
            }
        lsum += rs;   // cross-lane reduce deferred to after the loop

        // P^T pack to LDS (per-wave, same-wave read-back)
        #pragma unroll
        for (int mt = 0; mt < 4; mt++) {
            __hip_bfloat162 p01 = __float22bfloat162_rn(float2{sacc[mt][0], sacc[mt][1]});
            __hip_bfloat162 p23 = __float22bfloat162_rn(float2{sacc[mt][2], sacc[mt][3]});
            uint2 pk;
            pk.x = *reinterpret_cast<unsigned int*>(&p01);
            pk.y = *reinterpret_cast<unsigned int*>(&p23);
            *(uint2*)&Pt[w][c][mt * 16 + qd * 4] = pk;
        }
        bf16x8 pf[2];
        #pragma unroll
        for (int ks = 0; ks < 2; ks++)
            pf[ks] = *(const bf16x8*)&Pt[w][c][ks * 32 + qd * 8];

        // O^T += V^T . P^T (V read through the slot XOR swizzle)
        __builtin_amdgcn_s_setprio(1);
        #pragma unroll
        for (int mt = 0; mt < 6; mt++)
            #pragma unroll
            for (int ks = 0; ks < 2; ks++) {
                const int row = mt * 16 + c;
                bf16x8 vf = *(const bf16x8*)&Vt[row][(((ks << 2) + qd) ^ (c & 7)) << 3];
                oacc[mt] = __builtin_amdgcn_mfma_f32_16x16x32_bf16(
                    vf, pf[ks], oacc[mt], 0, 0, 0);
            }
        __builtin_amdgcn_s_setprio(0);
    }

    // Hoisted column-sum reduce across qd groups (lanes c, c+16, c+32, c+48)
    lsum += __shfl_xor(lsum, 16);
    lsum += __shfl_xor(lsum, 32);

    const float linv = 1.0f / lsum;
    unsigned short* orow = ob + ((size_t)(b * HWc + q0 + w * 16 + c)) * Cc + h * HDc;
    #pragma unroll
    for (int mt = 0; mt < 6; mt++) {
        f32x4 val = oacc[mt] * linv;
        ushort4 pk;
        pk.x = f2bf(val[0]); pk.y = f2bf(val[1]);
        pk.z = f2bf(val[2]); pk.w = f2bf(val[3]);
        *(ushort4*)&orow[mt * 16 + qd * 4] = pk;
    }
}

// ---------------------------------------------------------------------------
// Kernel 3: out = o @ Wproj^T + bias — r19 champion verbatim (2-barrier,
// single buffer, BK=32, XCD-chunked 1D grid).
// ---------------------------------------------------------------------------
__global__ __launch_bounds__(256) void proj_mfma_T64(
    const unsigned short* __restrict__ Wb, const unsigned short* __restrict__ Ab,
    const float* __restrict__ bias, float* __restrict__ out)
{
    __shared__ unsigned short Al[128 * 32];
    __shared__ unsigned short Bl[64 * 32];
    const int tid  = threadIdx.x;
    const int lane = tid & 63;
    const int w    = tid >> 6;
    const int c    = lane & 15, qd = lane >> 4;
    const int wm   = w & 1, wn = w >> 1;

    const int bid = blockIdx.x;
    const int xcd = bid & 7;
    const int jj  = bid >> 3;                  // 0..95
    const int xt  = (xcd << 4) + (jj & 15);    // token tile 0..127
    const int yt  = jj >> 4;                   // feature tile 0..5
    const int m0  = yt << 7;                   // out-feature base (0..640)
    const int n0  = xt << 6;                   // token base (64-tile)

    const int srow = (w << 5) + (lane >> 2);
    const int sseg = (lane & 3) << 3;
    const unsigned short* Ag = Wb + (size_t)(m0 + srow) * Cc + sseg;
    unsigned short* Adst = &Al[(w << 5) * 32];
    const int brow = (w << 4) + (lane >> 2);
    const unsigned short* Bg = Ab + (size_t)(n0 + brow) * Cc + sseg;
    unsigned short* Bdst = &Bl[(w << 4) * 32];

    f32x4 acc[4][2];
    #pragma unroll
    for (int i = 0; i < 4; i++)
        #pragma unroll
        for (int j = 0; j < 2; j++) acc[i][j] = (f32x4)0.f;

    for (int k0 = 0; k0 < Cc; k0 += 32) {
        __syncthreads();
        __builtin_amdgcn_global_load_lds(GLOBAL_AS(Ag + k0),           LDS_AS(Adst),           16, 0, 0);
        __builtin_amdgcn_global_load_lds(GLOBAL_AS(Ag + 16 * Cc + k0), LDS_AS(Adst + 16 * 32), 16, 0, 0);
        __builtin_amdgcn_global_load_lds(GLOBAL_AS(Bg + k0),           LDS_AS(Bdst),           16, 0, 0);
        __syncthreads();

        bf16x8 af[4], bfr[2];
        #pragma unroll
        for (int mt = 0; mt < 4; mt++)
            af[mt] = *(const bf16x8*)&Al[((wm << 6) + mt * 16 + c) * 32 + qd * 8];
        #pragma unroll
        for (int nt = 0; nt < 2; nt++)
            bfr[nt] = *(const bf16x8*)&Bl[((wn << 5) + nt * 16 + c) * 32 + qd * 8];
        #pragma unroll
        for (int mt = 0; mt < 4; mt++)
            #pragma unroll
            for (int nt = 0; nt < 2; nt++)
                acc[mt][nt] = __builtin_amdgcn_mfma_f32_16x16x32_bf16(
                    af[mt], bfr[nt], acc[mt][nt], 0, 0, 0);
    }

    #pragma unroll
    for (int mt = 0; mt < 4; mt++) {
        const int f = m0 + (wm << 6) + mt * 16 + (qd << 2);
        const float4 b4 = *(const float4*)&bias[f];
        #pragma unroll
        for (int nt = 0; nt < 2; nt++) {
            const int t = n0 + (wn << 5) + nt * 16 + c;
            float4 val;
            val.x = acc[mt][nt][0] + b4.x;
            val.y = acc[mt][nt][1] + b4.y;
            val.z = acc[mt][nt][2] + b4.z;
            val.w = acc[mt][nt][3] + b4.w;
            *(float4*)&out[(size_t)t * Cc + f] = val;
        }
    }
}

// ---------------------------------------------------------------------------
extern "C" void kernel_launch(void* const* d_in, const int* in_sizes, int n_in,
                              void* d_out, int out_size, void* d_ws, size_t ws_size,
                              hipStream_t stream) {
    const float* x     = (const float*)d_in[0];
    const float* cs    = (const float*)d_in[1];
    const float* sn    = (const float*)d_in[2];
    const float* Wqkv  = (const float*)d_in[3];
    const float* Wproj = (const float*)d_in[4];
    const float* bproj = (const float*)d_in[5];
    float* out = (float*)d_out;

    const size_t per = (size_t)Bc * Hc * HWc * HDc;  // 6291456
    const size_t nx  = per;
    const size_t nwq = (size_t)3 * Cc * Cc;
    const size_t nwp = (size_t)Cc * Cc;

    unsigned short* xb  = (unsigned short*)d_ws;
    unsigned short* Wqb = xb + nx;
    unsigned short* Wpb = Wqb + nwq;
    unsigned short* q   = Wpb + nwp;
    unsigned short* k   = q + per;
    unsigned short* vt  = k + per;
    unsigned short* ob  = vt + per;

    const int nx4 = (int)(nx / 4), nwq4 = (int)(nwq / 4), nwp4 = (int)(nwp / 4);
    const int ntot = nx4 + nwq4 + nwp4;
    cast_all<<<dim3((ntot + 255) / 256), 256, 0, stream>>>(
        x, Wqkv, Wproj, xb, Wqb, Wpb, nx4, nwq4, nwp4);

    // qkv: 1D grid, XCD-chunked decode (8 xcd x 8 token-tiles x 18 feat-tiles)
    qkv_mfma_T<<<dim3(1152), 256, 0, stream>>>(Wqb, xb, cs, sn, q, k, vt);
    // attention: x = bh (XCD affinity), y = 32 q-tiles of 64 -> 1024 blocks
    attn_flash<<<dim3(32, 32), 256, 0, stream>>>(q, k, vt, ob);
    // proj: 1D grid, XCD-chunked decode (8 xcd x 16 token-tiles x 6 feat-tiles)
    proj_mfma_T64<<<dim3(768), 256, 0, stream>>>(Wpb, ob, bproj, out);
}